// Round 25
// baseline (53.635 us; speedup 1.0000x reference)
//
#include <hip/hip_runtime.h>

#define NN 4096
#define FIN 256
#define FOUT 64
#define NH 4

using f32x4 = __attribute__((ext_vector_type(4))) float;
using s16x8 = __attribute__((ext_vector_type(8))) short;
typedef unsigned long long u64;

__device__ __forceinline__ unsigned short f32_to_bf16_rne(float f) {
    unsigned b = __float_as_uint(f);
    b += 0x7FFFu + ((b >> 16) & 1u);
    return (unsigned short)(b >> 16);
}

// Kernel 1 (R17/R18-proven fusion): blocks 0..255 = Wh GEMM -> WhT, s1, s2,
// blockmax[h][nb]; blocks 256..4351 = adj bitmask pack. Disjoint outputs.
__global__ __launch_bounds__(256) void k_prep(
    const float* __restrict__ x, const float* __restrict__ W,
    const float* __restrict__ a, const int* __restrict__ adj,
    short* __restrict__ WhT, float* __restrict__ s1, float* __restrict__ s2,
    float* __restrict__ blockmax, u64* __restrict__ packed)
{
    __shared__ unsigned short xs[64 * 256];
    __shared__ unsigned short wt[64 * 256];
    __shared__ float s2red[16];
    const int bx = blockIdx.x;
    const int t = threadIdx.x;

    if (bx >= 256) {
        // ---- pack path (R14-proven) ----
        const int lane = t & 63;
        const int jc = t >> 6;
        const int row = bx - 256;
        const int g = lane >> 4;
        const int li = lane & 15;
        const int* ap = adj + (size_t)row * NN + jc * 1024 + lane * 4;
        int4 v0 = *(const int4*)(ap);
        int4 v1 = *(const int4*)(ap + 256);
        int4 v2 = *(const int4*)(ap + 512);
        int4 v3 = *(const int4*)(ap + 768);
        u64 words[4];
        int4 vv[4] = {v0, v1, v2, v3};
        #pragma unroll
        for (int k = 0; k < 4; ++k) {
            unsigned b = (vv[k].x != 0 ? 1u : 0u) | (vv[k].y != 0 ? 2u : 0u)
                       | (vv[k].z != 0 ? 4u : 0u) | (vv[k].w != 0 ? 8u : 0u);
            u64 field = (u64)b << (4 * li);
            field |= __shfl_xor(field, 1, 64);
            field |= __shfl_xor(field, 2, 64);
            field |= __shfl_xor(field, 4, 64);
            field |= __shfl_xor(field, 8, 64);
            words[k] = field;
        }
        if (li == 0) {
            #pragma unroll
            for (int k = 0; k < 4; ++k)
                packed[(size_t)(jc * 16 + 4 * k + g) * NN + row] = words[k];
        }
        return;
    }

    // ---- wh path (R15-proven) ----
    const int nb = bx & 63, h = bx >> 6;
    const int n0 = nb * 64;
    {
        const float4* xg = reinterpret_cast<const float4*>(x + (size_t)n0 * FIN);
        for (int k = t; k < 64 * FIN / 4; k += 256) {
            float4 v = xg[k];
            int row = k >> 6, fq = k & 63;
            u64 pk = (u64)f32_to_bf16_rne(v.x) | ((u64)f32_to_bf16_rne(v.y) << 16)
                   | ((u64)f32_to_bf16_rne(v.z) << 32) | ((u64)f32_to_bf16_rne(v.w) << 48);
            int byte = (row * 512 + fq * 8) ^ ((row & 7) << 4);
            *(u64*)((char*)xs + byte) = pk;
        }
        const float* Wg = W + (size_t)h * FIN * FOUT;
        for (int k = t; k < FIN * FOUT; k += 256) {
            int f = k >> 6, o = k & 63;
            unsigned short wv = f32_to_bf16_rne(Wg[k]);
            int byte = (o * 512 + f * 2) ^ ((o & 7) << 4);
            *(unsigned short*)((char*)wt + byte) = wv;
        }
    }
    __syncthreads();
    const int lane = t & 63, wv_ = t >> 6;
    const int rowA = lane & 15;
    const int kq = (lane >> 4) * 8;
    const int i0 = wv_ * 16;
    f32x4 acc[4];
    #pragma unroll
    for (int c = 0; c < 4; ++c) acc[c] = (f32x4){0.f, 0.f, 0.f, 0.f};
    const int arow = i0 + rowA;
    #pragma unroll
    for (int kb = 0; kb < FIN; kb += 32) {
        int ab = (arow * 512 + (kb + kq) * 2) ^ ((arow & 7) << 4);
        s16x8 af = *(const s16x8*)((char*)xs + ab);
        #pragma unroll
        for (int c = 0; c < 4; ++c) {
            int col = c * 16 + rowA;
            int bb = (col * 512 + (kb + kq) * 2) ^ ((col & 7) << 4);
            s16x8 bf = *(const s16x8*)((char*)wt + bb);
            acc[c] = __builtin_amdgcn_mfma_f32_16x16x32_bf16(af, bf, acc[c], 0, 0, 0);
        }
    }
    const int q0 = (lane >> 4) * 4;
    const float L2E = 1.4426950408889634f;
    float v1acc[4] = {0.f, 0.f, 0.f, 0.f}, v2acc[4] = {0.f, 0.f, 0.f, 0.f};
    #pragma unroll
    for (int c = 0; c < 4; ++c) {
        int col = c * 16 + rowA;
        float a1v = a[h * (2 * FOUT) + col];
        float a2v = a[h * (2 * FOUT) + FOUT + col];
        short* wp = WhT + ((size_t)(h * FOUT + col)) * NN + n0 + i0 + q0;
        alignas(8) unsigned short tmp[4];
        #pragma unroll
        for (int q = 0; q < 4; ++q) {
            float v = acc[c][q];
            tmp[q] = f32_to_bf16_rne(v);
            v1acc[q] = fmaf(v, a1v, v1acc[q]);
            v2acc[q] = fmaf(v, a2v, v2acc[q]);
        }
        __builtin_memcpy(wp, tmp, 8);
    }
    float wmax = -3.0e38f;
    #pragma unroll
    for (int q = 0; q < 4; ++q) {
        float v1 = v1acc[q] * L2E, v2 = v2acc[q] * L2E;
        #pragma unroll
        for (int d = 1; d < 16; d <<= 1) {
            v1 += __shfl_xor(v1, d, 64);
            v2 += __shfl_xor(v2, d, 64);
        }
        if (rowA == 0) {
            int n = n0 + i0 + q0 + q;
            s1[h * NN + n] = v1;
            s2[h * NN + n] = v2;
            wmax = fmaxf(wmax, v2);
        }
    }
    if (rowA == 0) s2red[wv_ * 4 + (lane >> 4)] = wmax;
    __syncthreads();
    if (t == 0) {
        float m = s2red[0];
        #pragma unroll
        for (int i = 1; i < 16; ++i) m = fmaxf(m, s2red[i]);
        blockmax[h * 64 + nb] = m;
    }
}

// Kernel 2 (R25 = R24 + depth-2 stage prefetch): body t issues loads for tile
// t+2, ds_writes tile t+1's values (loaded one full body ago -> vmcnt wait is
// a no-op), computes tile t. Same 64KB LDS + two-stage merge as R24.
__global__ __launch_bounds__(1024, 4) void k_attn(
    const u64* __restrict__ packed, const short* __restrict__ WhT,
    const float* __restrict__ s1, const float* __restrict__ blockmax,
    const float* __restrict__ s2, float* __restrict__ out)
{
    __shared__ __align__(16) char smraw[65536];
    const int t = threadIdx.x;
    const int lane = t & 63;
    const int wid = t >> 6;
    const int rg = wid >> 2;
    const int jq = wid & 3;
    const int ib64 = blockIdx.x;
    const int h = blockIdx.y;
    const int row16 = lane & 15;
    const int kbase = (lane >> 4) * 8;
    const int irow = ib64 * 64 + rg * 16 + row16;

    float bm = blockmax[h * 64 + lane];
    #pragma unroll
    for (int d = 32; d >= 1; d >>= 1) bm = fmaxf(bm, __shfl_xor(bm, d, 64));
    const float s1v = s1[h * NN + irow];
    const float ttv = s1v + bm;
    const float M = fmaxf(ttv, 0.2f * ttv);
    const float c1v = s1v - M;
    const float c2v = fmaf(0.2f, s1v, -M);

    f32x4 acc[4], acc_l;
    #pragma unroll
    for (int c = 0; c < 4; ++c) acc[c] = (f32x4){0.f, 0.f, 0.f, 0.f};
    acc_l = (f32x4){0.f, 0.f, 0.f, 0.f};
    s16x8 ones;
    #pragma unroll
    for (int i = 0; i < 8; ++i) ones[i] = (short)0x3F80;   // bf16 1.0

    const float* s2q = s2 + h * NN + kbase;
    const u64*   mb  = packed + irow;

    const int gt = rg * 64 + lane;
    const int so = gt >> 3;
    const int sj = (gt & 7) * 8;
    const short* wsrc = WhT + (size_t)h * FOUT * NN;
    char* btb = smraw + jq * 16384;
    const int wb0 = (so * 128 + sj * 2) ^ ((so & 7) << 4);
    const int wb1 = ((so + 32) * 128 + sj * 2) ^ ((so & 7) << 4);

    int rd[4][2];
    #pragma unroll
    for (int c = 0; c < 4; ++c) {
        int o = c * 16 + row16;
        #pragma unroll
        for (int hf = 0; hf < 2; ++hf)
            rd[c][hf] = (o * 128 + (hf * 32 + kbase) * 2) ^ ((o & 7) << 4);
    }

    auto mk = [&](float sa, float sb, unsigned bits, int q0) -> unsigned {
        float e0 = fmaxf(c1v + sa, fmaf(0.2f, sa, c2v));
        float e1 = fmaxf(c1v + sb, fmaf(0.2f, sb, c2v));
        float p0 = __builtin_amdgcn_exp2f(e0);
        float p1 = __builtin_amdgcn_exp2f(e1);
        p0 = (bits & (1u << q0)) ? p0 : 0.f;
        p1 = (bits & (2u << q0)) ? p1 : 0.f;
        unsigned pk;
        asm("v_cvt_pk_bf16_f32 %0, %1, %2" : "=v"(pk) : "v"(p0), "v"(p1));
        return pk;
    };

    const int jbase = jq * 1024;
    // body(t): stC holds tile t+1 data (loaded last body). Issues loads for
    // tile t+2 (jb+128, wrapped), writes stC to btw, computes tile t from btr.
    auto body = [&](int jb, char* btr, char* btw, u64 cm, f32x4 (&cs)[4],
                    u64& nm, f32x4 (&ns)[4], s16x8& stC0, s16x8& stC1) {
        int jn = jb + 64;
        int jpf = (jn < jbase + 1024) ? jn : jbase;          // mask/s2: tile t+1
        int jp2 = jb + 128;
        if (jp2 >= jbase + 1024) jp2 -= 1024;                // stage: tile t+2 (wrap-safe)
        // (1) issue tile t+2 stage loads
        s16x8 tn0 = *(const s16x8*)(wsrc + (size_t)so * NN + jp2 + sj);
        s16x8 tn1 = *(const s16x8*)(wsrc + (size_t)(so + 32) * NN + jp2 + sj);
        // (2) issue next-iter mask + s2
        nm = mb[(size_t)(jpf >> 6) * NN];
        ns[0] = *(const f32x4*)(s2q + jpf);
        ns[1] = *(const f32x4*)(s2q + jpf + 4);
        ns[2] = *(const f32x4*)(s2q + jpf + 32);
        ns[3] = *(const f32x4*)(s2q + jpf + 36);
        // (3) score phase -> A fragments
        unsigned ml8 = ((unsigned)cm >> kbase) & 0xFFu;
        unsigned mh8 = ((unsigned)(cm >> 32) >> kbase) & 0xFFu;
        s16x8 A0, A1;
        unsigned* A0u = reinterpret_cast<unsigned*>(&A0);
        unsigned* A1u = reinterpret_cast<unsigned*>(&A1);
        A0u[0] = mk(cs[0][0], cs[0][1], ml8, 0);
        A0u[1] = mk(cs[0][2], cs[0][3], ml8, 2);
        A0u[2] = mk(cs[1][0], cs[1][1], ml8, 4);
        A0u[3] = mk(cs[1][2], cs[1][3], ml8, 6);
        A1u[0] = mk(cs[2][0], cs[2][1], mh8, 0);
        A1u[1] = mk(cs[2][2], cs[2][3], mh8, 2);
        A1u[2] = mk(cs[3][0], cs[3][1], mh8, 4);
        A1u[3] = mk(cs[3][2], cs[3][3], mh8, 6);
        // (4) commit tile t+1 (loaded LAST body -> vmcnt long elapsed)
        *(s16x8*)(btw + wb0) = stC0;
        *(s16x8*)(btw + wb1) = stC1;
        stC0 = tn0;
        stC1 = tn1;
        // (5) B frags (tile t) + MFMAs
        s16x8 b00 = *(const s16x8*)(btr + rd[0][0]);
        s16x8 b01 = *(const s16x8*)(btr + rd[0][1]);
        s16x8 b10 = *(const s16x8*)(btr + rd[1][0]);
        s16x8 b11 = *(const s16x8*)(btr + rd[1][1]);
        s16x8 b20 = *(const s16x8*)(btr + rd[2][0]);
        s16x8 b21 = *(const s16x8*)(btr + rd[2][1]);
        s16x8 b30 = *(const s16x8*)(btr + rd[3][0]);
        s16x8 b31 = *(const s16x8*)(btr + rd[3][1]);
        acc_l  = __builtin_amdgcn_mfma_f32_16x16x32_bf16(A0, ones, acc_l, 0, 0, 0);
        acc_l  = __builtin_amdgcn_mfma_f32_16x16x32_bf16(A1, ones, acc_l, 0, 0, 0);
        acc[0] = __builtin_amdgcn_mfma_f32_16x16x32_bf16(A0, b00, acc[0], 0, 0, 0);
        acc[0] = __builtin_amdgcn_mfma_f32_16x16x32_bf16(A1, b01, acc[0], 0, 0, 0);
        acc[1] = __builtin_amdgcn_mfma_f32_16x16x32_bf16(A0, b10, acc[1], 0, 0, 0);
        acc[1] = __builtin_amdgcn_mfma_f32_16x16x32_bf16(A1, b11, acc[1], 0, 0, 0);
        acc[2] = __builtin_amdgcn_mfma_f32_16x16x32_bf16(A0, b20, acc[2], 0, 0, 0);
        acc[2] = __builtin_amdgcn_mfma_f32_16x16x32_bf16(A1, b21, acc[2], 0, 0, 0);
        acc[3] = __builtin_amdgcn_mfma_f32_16x16x32_bf16(A0, b30, acc[3], 0, 0, 0);
        acc[3] = __builtin_amdgcn_mfma_f32_16x16x32_bf16(A1, b31, acc[3], 0, 0, 0);
    };

    // prologue: tile 0 staged directly; tile 1 loads issued into stC
    u64 m0, m1;
    f32x4 sv0[4], sv1[4];
    s16x8 stC0, stC1;
    int jb = jbase;
    {
        s16x8 st0 = *(const s16x8*)(wsrc + (size_t)so * NN + jb + sj);
        s16x8 st1 = *(const s16x8*)(wsrc + (size_t)(so + 32) * NN + jb + sj);
        *(s16x8*)(btb + wb0) = st0;
        *(s16x8*)(btb + wb1) = st1;
        stC0 = *(const s16x8*)(wsrc + (size_t)so * NN + jb + 64 + sj);
        stC1 = *(const s16x8*)(wsrc + (size_t)(so + 32) * NN + jb + 64 + sj);
        m0 = mb[(size_t)(jb >> 6) * NN];
        sv0[0] = *(const f32x4*)(s2q + jb);
        sv0[1] = *(const f32x4*)(s2q + jb + 4);
        sv0[2] = *(const f32x4*)(s2q + jb + 32);
        sv0[3] = *(const f32x4*)(s2q + jb + 36);
    }
    __syncthreads();
    #pragma unroll 1
    for (int it = 0; it < 8; ++it) {
        body(jb, btb, btb + 8192, m0, sv0, m1, sv1, stC0, stC1);
        __syncthreads();
        body(jb + 64, btb + 8192, btb, m1, sv1, m0, sv0, stC0, stC1);
        __syncthreads();
        jb += 128;
    }

    // ---- two-stage in-LDS merge (R24-proven) ----
    const int r4 = (lane >> 4) * 4;
    if (jq >= 2) {
        float* mw = (float*)smraw + (rg * 2 + (jq - 2)) * 1040;
        #pragma unroll
        for (int c = 0; c < 4; ++c)
            #pragma unroll
            for (int q = 0; q < 4; ++q)
                mw[(r4 + q) * 64 + c * 16 + row16] = acc[c][q];
        if (row16 == 0) {
            #pragma unroll
            for (int q = 0; q < 4; ++q) mw[1024 + r4 + q] = acc_l[q];
        }
    }
    __syncthreads();
    if (jq < 2) {
        const float* md = (const float*)smraw + (rg * 2 + jq) * 1040;
        #pragma unroll
        for (int c = 0; c < 4; ++c)
            #pragma unroll
            for (int q = 0; q < 4; ++q)
                acc[c][q] += md[(r4 + q) * 64 + c * 16 + row16];
        #pragma unroll
        for (int q = 0; q < 4; ++q) acc_l[q] += md[1024 + r4 + q];
    }
    __syncthreads();
    if (jq == 1) {
        float* mw = (float*)smraw + rg * 1040;
        #pragma unroll
        for (int c = 0; c < 4; ++c)
            #pragma unroll
            for (int q = 0; q < 4; ++q)
                mw[(r4 + q) * 64 + c * 16 + row16] = acc[c][q];
        if (row16 == 0) {
            #pragma unroll
            for (int q = 0; q < 4; ++q) mw[1024 + r4 + q] = acc_l[q];
        }
    }
    __syncthreads();
    if (jq == 0) {
        const float* md = (const float*)smraw + rg * 1040;
        float l[4];
        #pragma unroll
        for (int q = 0; q < 4; ++q)
            l[q] = 1.0f / (acc_l[q] + md[1024 + r4 + q]);
        #pragma unroll
        for (int c = 0; c < 4; ++c) {
            #pragma unroll
            for (int q = 0; q < 4; ++q) {
                int r = r4 + q;
                int o = c * 16 + row16;
                float v = acc[c][q] + md[r * 64 + o];
                int n = ib64 * 64 + rg * 16 + r;
                out[(size_t)n * (NH * FOUT) + h * FOUT + o] = v * l[q];
            }
        }
    }
}

extern "C" void kernel_launch(void* const* d_in, const int* in_sizes, int n_in,
                              void* d_out, int out_size, void* d_ws, size_t ws_size,
                              hipStream_t stream) {
    (void)in_sizes; (void)n_in; (void)out_size; (void)ws_size;
    const float* x  = (const float*)d_in[0];
    const int*  adj = (const int*)d_in[1];
    const float* W  = (const float*)d_in[2];
    const float* a  = (const float*)d_in[3];
    float* out = (float*)d_out;
    char* ws = (char*)d_ws;

    size_t off = 0;
    short* WhT      = (short*)(ws + off); off += (size_t)NH * FOUT * NN * 2;   // 2 MB
    float* s1       = (float*)(ws + off); off += (size_t)NH * NN * 4;          // 64 KB
    float* s2       = (float*)(ws + off); off += (size_t)NH * NN * 4;          // 64 KB
    float* blockmax = (float*)(ws + off); off += (size_t)NH * 64 * 4;          // 1 KB
    u64* packed     = (u64*)(ws + off); off += (size_t)(NN / 64) * NN * 8;     // 2 MB

    k_prep<<<4352, 256, 0, stream>>>(x, W, a, adj, WhT, s1, s2, blockmax, packed);
    k_attn<<<dim3(64, NH), 1024, 0, stream>>>(packed, WhT, s1, blockmax, s2, out);
}

// Round 26
// 51.862 us; speedup vs baseline: 1.0342x; 1.0342x over previous
//
#include <hip/hip_runtime.h>

#define NN 4096
#define FIN 256
#define FOUT 64
#define NH 4

using f32x4 = __attribute__((ext_vector_type(4))) float;
using s16x8 = __attribute__((ext_vector_type(8))) short;
typedef unsigned long long u64;

__device__ __forceinline__ unsigned short f32_to_bf16_rne(float f) {
    unsigned b = __float_as_uint(f);
    b += 0x7FFFu + ((b >> 16) & 1u);
    return (unsigned short)(b >> 16);
}

// Kernel 1: fused prep. Blocks 0..255 = Wh GEMM (bf16 MFMA) -> WhT, s1, s2,
// blockmax[h][nb] (owner-written, no atomics); blocks 256..4351 = adj bitmask
// pack (coalesced int4 loads + 4-level shfl_xor assemble). Disjoint outputs;
// the pack HBM stream overlaps the GEMM compute.
__global__ __launch_bounds__(256) void k_prep(
    const float* __restrict__ x, const float* __restrict__ W,
    const float* __restrict__ a, const int* __restrict__ adj,
    short* __restrict__ WhT, float* __restrict__ s1, float* __restrict__ s2,
    float* __restrict__ blockmax, u64* __restrict__ packed)
{
    __shared__ unsigned short xs[64 * 256];
    __shared__ unsigned short wt[64 * 256];
    __shared__ float s2red[16];
    const int bx = blockIdx.x;
    const int t = threadIdx.x;

    if (bx >= 256) {
        // ---- pack path ----
        const int lane = t & 63;
        const int jc = t >> 6;
        const int row = bx - 256;
        const int g = lane >> 4;
        const int li = lane & 15;
        const int* ap = adj + (size_t)row * NN + jc * 1024 + lane * 4;
        int4 v0 = *(const int4*)(ap);
        int4 v1 = *(const int4*)(ap + 256);
        int4 v2 = *(const int4*)(ap + 512);
        int4 v3 = *(const int4*)(ap + 768);
        u64 words[4];
        int4 vv[4] = {v0, v1, v2, v3};
        #pragma unroll
        for (int k = 0; k < 4; ++k) {
            unsigned b = (vv[k].x != 0 ? 1u : 0u) | (vv[k].y != 0 ? 2u : 0u)
                       | (vv[k].z != 0 ? 4u : 0u) | (vv[k].w != 0 ? 8u : 0u);
            u64 field = (u64)b << (4 * li);
            field |= __shfl_xor(field, 1, 64);
            field |= __shfl_xor(field, 2, 64);
            field |= __shfl_xor(field, 4, 64);
            field |= __shfl_xor(field, 8, 64);
            words[k] = field;
        }
        if (li == 0) {
            #pragma unroll
            for (int k = 0; k < 4; ++k)
                packed[(size_t)(jc * 16 + 4 * k + g) * NN + row] = words[k];
        }
        return;
    }

    // ---- wh path ----
    const int nb = bx & 63, h = bx >> 6;
    const int n0 = nb * 64;
    {
        const float4* xg = reinterpret_cast<const float4*>(x + (size_t)n0 * FIN);
        for (int k = t; k < 64 * FIN / 4; k += 256) {
            float4 v = xg[k];
            int row = k >> 6, fq = k & 63;
            u64 pk = (u64)f32_to_bf16_rne(v.x) | ((u64)f32_to_bf16_rne(v.y) << 16)
                   | ((u64)f32_to_bf16_rne(v.z) << 32) | ((u64)f32_to_bf16_rne(v.w) << 48);
            int byte = (row * 512 + fq * 8) ^ ((row & 7) << 4);
            *(u64*)((char*)xs + byte) = pk;
        }
        const float* Wg = W + (size_t)h * FIN * FOUT;
        for (int k = t; k < FIN * FOUT; k += 256) {
            int f = k >> 6, o = k & 63;
            unsigned short wv = f32_to_bf16_rne(Wg[k]);
            int byte = (o * 512 + f * 2) ^ ((o & 7) << 4);
            *(unsigned short*)((char*)wt + byte) = wv;
        }
    }
    __syncthreads();
    const int lane = t & 63, wv_ = t >> 6;
    const int rowA = lane & 15;
    const int kq = (lane >> 4) * 8;
    const int i0 = wv_ * 16;
    f32x4 acc[4];
    #pragma unroll
    for (int c = 0; c < 4; ++c) acc[c] = (f32x4){0.f, 0.f, 0.f, 0.f};
    const int arow = i0 + rowA;
    #pragma unroll
    for (int kb = 0; kb < FIN; kb += 32) {
        int ab = (arow * 512 + (kb + kq) * 2) ^ ((arow & 7) << 4);
        s16x8 af = *(const s16x8*)((char*)xs + ab);
        #pragma unroll
        for (int c = 0; c < 4; ++c) {
            int col = c * 16 + rowA;
            int bb = (col * 512 + (kb + kq) * 2) ^ ((col & 7) << 4);
            s16x8 bf = *(const s16x8*)((char*)wt + bb);
            acc[c] = __builtin_amdgcn_mfma_f32_16x16x32_bf16(af, bf, acc[c], 0, 0, 0);
        }
    }
    const int q0 = (lane >> 4) * 4;
    const float L2E = 1.4426950408889634f;
    float v1acc[4] = {0.f, 0.f, 0.f, 0.f}, v2acc[4] = {0.f, 0.f, 0.f, 0.f};
    #pragma unroll
    for (int c = 0; c < 4; ++c) {
        int col = c * 16 + rowA;
        float a1v = a[h * (2 * FOUT) + col];
        float a2v = a[h * (2 * FOUT) + FOUT + col];
        short* wp = WhT + ((size_t)(h * FOUT + col)) * NN + n0 + i0 + q0;
        alignas(8) unsigned short tmp[4];
        #pragma unroll
        for (int q = 0; q < 4; ++q) {
            float v = acc[c][q];
            tmp[q] = f32_to_bf16_rne(v);
            v1acc[q] = fmaf(v, a1v, v1acc[q]);
            v2acc[q] = fmaf(v, a2v, v2acc[q]);
        }
        __builtin_memcpy(wp, tmp, 8);
    }
    float wmax = -3.0e38f;
    #pragma unroll
    for (int q = 0; q < 4; ++q) {
        float v1 = v1acc[q] * L2E, v2 = v2acc[q] * L2E;
        #pragma unroll
        for (int d = 1; d < 16; d <<= 1) {
            v1 += __shfl_xor(v1, d, 64);
            v2 += __shfl_xor(v2, d, 64);
        }
        if (rowA == 0) {
            int n = n0 + i0 + q0 + q;
            s1[h * NN + n] = v1;
            s2[h * NN + n] = v2;
            wmax = fmaxf(wmax, v2);
        }
    }
    if (rowA == 0) s2red[wv_ * 4 + (lane >> 4)] = wmax;
    __syncthreads();
    if (t == 0) {
        float m = s2red[0];
        #pragma unroll
        for (int i = 1; i < 16; ++i) m = fmaxf(m, s2red[i]);
        blockmax[h * 64 + nb] = m;
    }
}

// Kernel 2: fused masked-softmax + PV. 1024-thread block = 4 row-groups x
// 4 j-quarters; per-group double-buffered XOR-swizzled LDS B-tile; in-register
// P build in MFMA A-fragment layout; l-sum via all-ones MFMA column; 64KB-exact
// static LDS (two-stage in-LDS merge) so LDS never caps residency.
__global__ __launch_bounds__(1024, 4) void k_attn(
    const u64* __restrict__ packed, const short* __restrict__ WhT,
    const float* __restrict__ s1, const float* __restrict__ blockmax,
    const float* __restrict__ s2, float* __restrict__ out)
{
    __shared__ __align__(16) char smraw[65536];   // 4 jq btiles (dbuf) / merge area
    const int t = threadIdx.x;
    const int lane = t & 63;
    const int wid = t >> 6;        // 0..15
    const int rg = wid >> 2;       // row group
    const int jq = wid & 3;        // j quarter
    const int ib64 = blockIdx.x;
    const int h = blockIdx.y;
    const int row16 = lane & 15;
    const int kbase = (lane >> 4) * 8;
    const int irow = ib64 * 64 + rg * 16 + row16;

    float bm = blockmax[h * 64 + lane];
    #pragma unroll
    for (int d = 32; d >= 1; d >>= 1) bm = fmaxf(bm, __shfl_xor(bm, d, 64));
    const float s1v = s1[h * NN + irow];
    const float ttv = s1v + bm;
    const float M = fmaxf(ttv, 0.2f * ttv);
    const float c1v = s1v - M;
    const float c2v = fmaf(0.2f, s1v, -M);

    f32x4 acc[4], acc_l;
    #pragma unroll
    for (int c = 0; c < 4; ++c) acc[c] = (f32x4){0.f, 0.f, 0.f, 0.f};
    acc_l = (f32x4){0.f, 0.f, 0.f, 0.f};
    s16x8 ones;
    #pragma unroll
    for (int i = 0; i < 8; ++i) ones[i] = (short)0x3F80;   // bf16 1.0

    const float* s2q = s2 + h * NN + kbase;
    const u64*   mb  = packed + irow;

    const int gt = rg * 64 + lane;
    const int so = gt >> 3;
    const int sj = (gt & 7) * 8;
    const short* wsrc = WhT + (size_t)h * FOUT * NN;
    char* btb = smraw + jq * 16384;
    const int wb0 = (so * 128 + sj * 2) ^ ((so & 7) << 4);
    const int wb1 = ((so + 32) * 128 + sj * 2) ^ ((so & 7) << 4);

    int rd[4][2];
    #pragma unroll
    for (int c = 0; c < 4; ++c) {
        int o = c * 16 + row16;
        #pragma unroll
        for (int hf = 0; hf < 2; ++hf)
            rd[c][hf] = (o * 128 + (hf * 32 + kbase) * 2) ^ ((o & 7) << 4);
    }

    auto mk = [&](float sa, float sb, unsigned bits, int q0) -> unsigned {
        float e0 = fmaxf(c1v + sa, fmaf(0.2f, sa, c2v));
        float e1 = fmaxf(c1v + sb, fmaf(0.2f, sb, c2v));
        float p0 = __builtin_amdgcn_exp2f(e0);
        float p1 = __builtin_amdgcn_exp2f(e1);
        p0 = (bits & (1u << q0)) ? p0 : 0.f;
        p1 = (bits & (2u << q0)) ? p1 : 0.f;
        unsigned pk;
        asm("v_cvt_pk_bf16_f32 %0, %1, %2" : "=v"(pk) : "v"(p0), "v"(p1));
        return pk;
    };

    const int jbase = jq * 1024;
    auto body = [&](int jb, char* btr, char* btw, u64 cm, f32x4 (&cs)[4],
                    u64& nm, f32x4 (&ns)[4]) {
        int jn = jb + 64;
        int jpf = (jn < jbase + 1024) ? jn : jbase;
        s16x8 st0 = *(const s16x8*)(wsrc + (size_t)so * NN + jpf + sj);
        s16x8 st1 = *(const s16x8*)(wsrc + (size_t)(so + 32) * NN + jpf + sj);
        nm = mb[(size_t)(jpf >> 6) * NN];
        ns[0] = *(const f32x4*)(s2q + jpf);
        ns[1] = *(const f32x4*)(s2q + jpf + 4);
        ns[2] = *(const f32x4*)(s2q + jpf + 32);
        ns[3] = *(const f32x4*)(s2q + jpf + 36);
        unsigned ml8 = ((unsigned)cm >> kbase) & 0xFFu;
        unsigned mh8 = ((unsigned)(cm >> 32) >> kbase) & 0xFFu;
        s16x8 A0, A1;
        unsigned* A0u = reinterpret_cast<unsigned*>(&A0);
        unsigned* A1u = reinterpret_cast<unsigned*>(&A1);
        A0u[0] = mk(cs[0][0], cs[0][1], ml8, 0);
        A0u[1] = mk(cs[0][2], cs[0][3], ml8, 2);
        A0u[2] = mk(cs[1][0], cs[1][1], ml8, 4);
        A0u[3] = mk(cs[1][2], cs[1][3], ml8, 6);
        A1u[0] = mk(cs[2][0], cs[2][1], mh8, 0);
        A1u[1] = mk(cs[2][2], cs[2][3], mh8, 2);
        A1u[2] = mk(cs[3][0], cs[3][1], mh8, 4);
        A1u[3] = mk(cs[3][2], cs[3][3], mh8, 6);
        *(s16x8*)(btw + wb0) = st0;
        *(s16x8*)(btw + wb1) = st1;
        s16x8 b00 = *(const s16x8*)(btr + rd[0][0]);
        s16x8 b01 = *(const s16x8*)(btr + rd[0][1]);
        s16x8 b10 = *(const s16x8*)(btr + rd[1][0]);
        s16x8 b11 = *(const s16x8*)(btr + rd[1][1]);
        s16x8 b20 = *(const s16x8*)(btr + rd[2][0]);
        s16x8 b21 = *(const s16x8*)(btr + rd[2][1]);
        s16x8 b30 = *(const s16x8*)(btr + rd[3][0]);
        s16x8 b31 = *(const s16x8*)(btr + rd[3][1]);
        acc_l  = __builtin_amdgcn_mfma_f32_16x16x32_bf16(A0, ones, acc_l, 0, 0, 0);
        acc_l  = __builtin_amdgcn_mfma_f32_16x16x32_bf16(A1, ones, acc_l, 0, 0, 0);
        acc[0] = __builtin_amdgcn_mfma_f32_16x16x32_bf16(A0, b00, acc[0], 0, 0, 0);
        acc[0] = __builtin_amdgcn_mfma_f32_16x16x32_bf16(A1, b01, acc[0], 0, 0, 0);
        acc[1] = __builtin_amdgcn_mfma_f32_16x16x32_bf16(A0, b10, acc[1], 0, 0, 0);
        acc[1] = __builtin_amdgcn_mfma_f32_16x16x32_bf16(A1, b11, acc[1], 0, 0, 0);
        acc[2] = __builtin_amdgcn_mfma_f32_16x16x32_bf16(A0, b20, acc[2], 0, 0, 0);
        acc[2] = __builtin_amdgcn_mfma_f32_16x16x32_bf16(A1, b21, acc[2], 0, 0, 0);
        acc[3] = __builtin_amdgcn_mfma_f32_16x16x32_bf16(A0, b30, acc[3], 0, 0, 0);
        acc[3] = __builtin_amdgcn_mfma_f32_16x16x32_bf16(A1, b31, acc[3], 0, 0, 0);
    };

    u64 m0, m1;
    f32x4 sv0[4], sv1[4];
    int jb = jbase;
    {
        s16x8 st0 = *(const s16x8*)(wsrc + (size_t)so * NN + jb + sj);
        s16x8 st1 = *(const s16x8*)(wsrc + (size_t)(so + 32) * NN + jb + sj);
        *(s16x8*)(btb + wb0) = st0;
        *(s16x8*)(btb + wb1) = st1;
        m0 = mb[(size_t)(jb >> 6) * NN];
        sv0[0] = *(const f32x4*)(s2q + jb);
        sv0[1] = *(const f32x4*)(s2q + jb + 4);
        sv0[2] = *(const f32x4*)(s2q + jb + 32);
        sv0[3] = *(const f32x4*)(s2q + jb + 36);
    }
    __syncthreads();
    #pragma unroll 1
    for (int it = 0; it < 8; ++it) {
        body(jb, btb, btb + 8192, m0, sv0, m1, sv1);
        __syncthreads();
        body(jb + 64, btb + 8192, btb, m1, sv1, m0, sv0);
        __syncthreads();
        jb += 128;
    }

    // ---- two-stage in-LDS merge (33KB working set; btile dead) ----
    const int r4 = (lane >> 4) * 4;
    if (jq >= 2) {
        float* mw = (float*)smraw + (rg * 2 + (jq - 2)) * 1040;
        #pragma unroll
        for (int c = 0; c < 4; ++c)
            #pragma unroll
            for (int q = 0; q < 4; ++q)
                mw[(r4 + q) * 64 + c * 16 + row16] = acc[c][q];
        if (row16 == 0) {
            #pragma unroll
            for (int q = 0; q < 4; ++q) mw[1024 + r4 + q] = acc_l[q];
        }
    }
    __syncthreads();
    if (jq < 2) {
        const float* md = (const float*)smraw + (rg * 2 + jq) * 1040;
        #pragma unroll
        for (int c = 0; c < 4; ++c)
            #pragma unroll
            for (int q = 0; q < 4; ++q)
                acc[c][q] += md[(r4 + q) * 64 + c * 16 + row16];
        #pragma unroll
        for (int q = 0; q < 4; ++q) acc_l[q] += md[1024 + r4 + q];
    }
    __syncthreads();
    if (jq == 1) {
        float* mw = (float*)smraw + rg * 1040;
        #pragma unroll
        for (int c = 0; c < 4; ++c)
            #pragma unroll
            for (int q = 0; q < 4; ++q)
                mw[(r4 + q) * 64 + c * 16 + row16] = acc[c][q];
        if (row16 == 0) {
            #pragma unroll
            for (int q = 0; q < 4; ++q) mw[1024 + r4 + q] = acc_l[q];
        }
    }
    __syncthreads();
    if (jq == 0) {
        const float* md = (const float*)smraw + rg * 1040;
        float l[4];
        #pragma unroll
        for (int q = 0; q < 4; ++q)
            l[q] = 1.0f / (acc_l[q] + md[1024 + r4 + q]);
        #pragma unroll
        for (int c = 0; c < 4; ++c) {
            #pragma unroll
            for (int q = 0; q < 4; ++q) {
                int r = r4 + q;
                int o = c * 16 + row16;
                float v = acc[c][q] + md[r * 64 + o];
                int n = ib64 * 64 + rg * 16 + r;
                out[(size_t)n * (NH * FOUT) + h * FOUT + o] = v * l[q];
            }
        }
    }
}

extern "C" void kernel_launch(void* const* d_in, const int* in_sizes, int n_in,
                              void* d_out, int out_size, void* d_ws, size_t ws_size,
                              hipStream_t stream) {
    (void)in_sizes; (void)n_in; (void)out_size; (void)ws_size;
    const float* x  = (const float*)d_in[0];
    const int*  adj = (const int*)d_in[1];
    const float* W  = (const float*)d_in[2];
    const float* a  = (const float*)d_in[3];
    float* out = (float*)d_out;
    char* ws = (char*)d_ws;

    size_t off = 0;
    short* WhT      = (short*)(ws + off); off += (size_t)NH * FOUT * NN * 2;   // 2 MB
    float* s1       = (float*)(ws + off); off += (size_t)NH * NN * 4;          // 64 KB
    float* s2       = (float*)(ws + off); off += (size_t)NH * NN * 4;          // 64 KB
    float* blockmax = (float*)(ws + off); off += (size_t)NH * 64 * 4;          // 1 KB
    u64* packed     = (u64*)(ws + off); off += (size_t)(NN / 64) * NN * 8;     // 2 MB

    k_prep<<<4352, 256, 0, stream>>>(x, W, a, adj, WhT, s1, s2, blockmax, packed);
    k_attn<<<dim3(64, NH), 1024, 0, stream>>>(packed, WhT, s1, blockmax, s2, out);
}